// Round 11
// baseline (207.865 us; speedup 1.0000x reference)
//
#include <hip/hip_runtime.h>
#include <math.h>

typedef unsigned int   uint;
typedef unsigned short ushort;
typedef unsigned char  uchar;

#define N_NODES 50000
#define DIM     128
#define N_EDGES 800000
#define N_UID   4096
#define LN_EPS  1e-5f
#define RST     132   // padded LDS row stride for fp32 y (132*4 B)
#define XST     136   // padded LDS row stride for bf16 x
#define BSH     6     // bucket shift: 64-node buckets
#define BND     64    // nodes per bucket
#define NBUCK   782   // ceil(50000/64)
#define BCAP    1280  // per-bucket capacity (mean 1024, sigma~32 -> +8 sigma)
#define PCHUNK  2048  // edges per partition chunk
#define NCHUNK  ((N_EDGES + PCHUNK - 1) / PCHUNK)   // 391
#define PGRP    1563  // ceil(50000/32) quant groups of 32 rows
#define PADID   (PGRP * 32)   // 50016: pad row id; group PGRP has meta (0,0) -> exact 0
#define QROWS   (PADID + 32)  // rows allocated per Q buffer

typedef __attribute__((ext_vector_type(8))) short bf16x8;
typedef __attribute__((ext_vector_type(4))) float f32x4;
typedef __attribute__((ext_vector_type(4))) uint  u32x4;

// ---- bf16 pack (storage only; math fp32) ----
__device__ __forceinline__ uint pack_bf16(float a, float b) {   // RNE
    uint ua = __builtin_bit_cast(uint, a);
    uint ub = __builtin_bit_cast(uint, b);
    uint ra = (ua + 0x7fffu + ((ua >> 16) & 1u)) >> 16;
    uint rb = (ub + 0x7fffu + ((ub >> 16) & 1u)) >> 16;
    return ra | (rb << 16);
}

// ---------- prep: emb -> int8 with PER-32-ROW-GROUP meta, W -> bf16, zero bcur + pad metas ----------
// 512 threads. Blocks [0,PGRP): quantize one 32-row group; [PGRP,PGRP+24): W; last: misc.
__global__ __launch_bounds__(512) void prep_kernel(const float* __restrict__ emb,
                                                   uchar* __restrict__ Q0, float2* __restrict__ MG0,
                                                   const float* __restrict__ W, ushort* __restrict__ WB,
                                                   int* __restrict__ bcur,
                                                   float2* __restrict__ MG1, float2* __restrict__ MG2) {
    const int t = threadIdx.x, b = blockIdx.x;
    if (b < PGRP) {
        __shared__ float smn[32], smx[32];
        const int row = b * 32 + (t >> 4);
        const int seg = t & 15;
        const bool valid = row < N_NODES;
        float vs[8];
        float mn = 3.4e38f, mx = -3.4e38f;
        if (valid) {
            const float* rp = emb + (size_t)row * DIM + seg * 8;
            const float4 v0 = ((const float4*)rp)[0];
            const float4 v1 = ((const float4*)rp)[1];
            vs[0]=v0.x; vs[1]=v0.y; vs[2]=v0.z; vs[3]=v0.w;
            vs[4]=v1.x; vs[5]=v1.y; vs[6]=v1.z; vs[7]=v1.w;
            mn = vs[0]; mx = vs[0];
            #pragma unroll
            for (int j = 1; j < 8; ++j) { mn = fminf(mn, vs[j]); mx = fmaxf(mx, vs[j]); }
        }
        #pragma unroll
        for (int m = 1; m < 16; m <<= 1) {
            mn = fminf(mn, __shfl_xor(mn, m));
            mx = fmaxf(mx, __shfl_xor(mx, m));
        }
        if (seg == 0) { smn[t >> 4] = mn; smx[t >> 4] = mx; }
        __syncthreads();
        float gmn = smn[0], gmx = smx[0];
        #pragma unroll
        for (int i = 1; i < 32; ++i) { gmn = fminf(gmn, smn[i]); gmx = fmaxf(gmx, smx[i]); }
        const float rng = gmx - gmn;
        const float rcp = (rng > 0.0f) ? 255.0f / rng : 0.0f;
        if (valid) {
            uint bq[8];
            #pragma unroll
            for (int j = 0; j < 8; ++j)
                bq[j] = (uint)fminf(255.0f, fmaf(vs[j] - gmn, rcp, 0.5f));
            uint2 q;
            q.x = bq[0] | (bq[1] << 8) | (bq[2] << 16) | (bq[3] << 24);
            q.y = bq[4] | (bq[5] << 8) | (bq[6] << 16) | (bq[7] << 24);
            ((uint2*)(Q0 + (size_t)row * DIM))[seg] = q;
        }
        if (t == 0) MG0[b] = make_float2(rng * (1.0f / 255.0f), gmn);
    } else if (b < PGRP + 24) {
        const int i = (b - PGRP) * 512 + t;      // < 12288 exactly
        const float4 v = ((const float4*)W)[i];
        uint2 p;
        p.x = pack_bf16(v.x, v.y);
        p.y = pack_bf16(v.z, v.w);
        ((uint2*)WB)[i] = p;
    } else {
        for (int i = t; i < NBUCK; i += 512) bcur[i] = 0;
        if (t == 0) {                            // pad group: scale=offset=0 -> exact 0 contribution
            MG0[PGRP] = make_float2(0.0f, 0.0f);
            MG1[PGRP] = make_float2(0.0f, 0.0f);
            MG2[PGRP] = make_float2(0.0f, 0.0f);
        }
    }
}

// ---------- partition into fixed-capacity padded 64-node buckets ----------
__global__ __launch_bounds__(256) void part_kernel(const int* __restrict__ src, const int* __restrict__ dst,
                                                   int* __restrict__ bcur, int* __restrict__ pak) {
    __shared__ int h[NBUCK];
    __shared__ int base[NBUCK];
    __shared__ int cur[NBUCK];
    const int t  = threadIdx.x;
    const int e0 = blockIdx.x * PCHUNK;
    const int e1 = min(e0 + PCHUNK, N_EDGES);
    for (int i = t; i < NBUCK; i += 256) h[i] = 0;
    __syncthreads();
    for (int i = e0 + t; i < e1; i += 256)
        atomicAdd(&h[dst[i] >> BSH], 1);
    __syncthreads();
    for (int i = t; i < NBUCK; i += 256) {
        if (h[i]) base[i] = atomicAdd(&bcur[i], h[i]);
        cur[i] = 0;
    }
    __syncthreads();
    for (int i = e0 + t; i < e1; i += 256) {
        const int s = src[i], d = dst[i];
        const int b = d >> BSH;
        const int q = base[b] + atomicAdd(&cur[b], 1);
        if (q < BCAP)                               // +8 sigma guard (never fires)
            pak[b * BCAP + q] = (s << BSH) | (d & (BND - 1));
    }
}

// ---------- per-bucket CSR: count/scan/scatter in LDS; padded layout ----------
__global__ __launch_bounds__(256) void bucket_kernel(const int* __restrict__ pak, const int* __restrict__ bcur,
                                                     int* __restrict__ off, int* __restrict__ degv,
                                                     int* __restrict__ csr) {
    __shared__ int cnt[BND];
    __shared__ int pos[BND];
    const int b = blockIdx.x, t = threadIdx.x;
    const int e0 = b * BCAP;
    const int m  = min(bcur[b], BCAP);
    if (t < BND) cnt[t] = 0;
    __syncthreads();
    for (int i = t; i < m; i += 256) atomicAdd(&cnt[pak[e0 + i] & (BND - 1)], 1);
    __syncthreads();
    const int v = (t < BND) ? cnt[t] : 0;
    if (t < BND) pos[t] = v;
    __syncthreads();
    for (int o = 1; o < BND; o <<= 1) {
        int x = 0;
        if (t < BND && t >= o) x = pos[t - o];
        __syncthreads();
        if (t < BND) pos[t] += x;
        __syncthreads();
    }
    const int excl = (t < BND) ? (pos[t] - v) : 0;
    const int node = b * BND + t;
    if (t < BND && node < N_NODES) { off[node] = e0 + excl; degv[node] = v; }
    __syncthreads();
    if (t < BND) pos[t] = excl;                  // reuse as cursor
    __syncthreads();
    for (int i = t; i < m; i += 256) {
        const int p = pak[e0 + i];
        const int q = atomicAdd(&pos[p & (BND - 1)], 1);
        csr[e0 + q] = p >> BSH;
    }
}

// ---------- fused layer: int8 gather w/ LDS-resident GROUP meta + MFMA + LN + ELU ----------
// 512 thr, 32 nodes/block. Meta table (1564 x float2 = 12.5KB) staged to LDS once
// per block -> per-edge meta access is an LDS broadcast, NOT a memory request.
// This halves random line-requests/CU vs r5 (6520 -> ~3300): the request-slot
// occupancy model's prediction is dur 47 -> ~30us. Gather: 16-lane stream/node,
// 8 rows in flight, pad id -> group PGRP (s=o=0, exact zero contribution).
// Phase 3 computes the block's OWN 32-row group meta (free in-block reduce).
// C/D: col = lane&15, row = (lane>>4)*4 + reg   [measured m89]
template <bool OUT_FP32>
__global__ __launch_bounds__(512, 4) void layer_kernel(
    const uchar* __restrict__ qin, const float2* __restrict__ mgin,
    uchar* __restrict__ qout, float2* __restrict__ mgout, float* __restrict__ fpout,
    const int* __restrict__ off, const int* __restrict__ degv,
    const int* __restrict__ csr, const int* __restrict__ uidmap,
    const ushort* __restrict__ wb, const float* __restrict__ bias,
    const float* __restrict__ gamma, const float* __restrict__ beta, int nrows)
{
    __shared__ ushort xs[32 * XST];     // 8704 B  bf16 x_mean
    __shared__ float  ys[32 * RST];     // 16896 B fp32 y
    __shared__ float2 metal[PGRP + 1];  // 12512 B input-buffer group meta
    __shared__ float  rmn[32], rmx[32]; // requant block reduce
    const int t = threadIdx.x;
    const int rows = blockIdx.x * 32;

    // ---- stage meta table to LDS (sequential, coalesced) ----
    for (int i = t; i < PGRP + 1; i += 512) metal[i] = mgin[i];
    __syncthreads();

    // ---- phase 1: aggregate (int8 gather, 8 rows in flight, meta from LDS) ----
    {
        const int lx   = t & 15;                 // covers elems lx*8 .. lx*8+7
        const int st   = t >> 4;                 // node slot 0..31
        const int slot = rows + st;
        const bool valid = slot < nrows;
        int n = 0;
        if (valid) n = uidmap ? uidmap[slot] : slot;
        const int d0 = off[n];
        const int deg = valid ? degv[n] : 0;
        const int total = deg + 1;               // self + neighbors

        float a[8] = {0,0,0,0,0,0,0,0};
        float O = 0.0f;
        const int rounds = (total + 7) >> 3;
        int id[8], idn[8];
        uint2 qv[8];

#define LIDS(ID, BASE) { _Pragma("unroll") for (int k = 0; k < 8; ++k) {        \
            const int pos = (BASE) + k;                                         \
            const int c = csr[d0 + ((pos > 0) ? pos - 1 : 0)];                  \
            ID[k] = (pos == 0) ? n : ((pos < total) ? c : PADID); } }

        LIDS(id, 0);
        for (int r = 0; r < rounds; ++r) {
            #pragma unroll
            for (int k = 0; k < 8; ++k)
                qv[k] = ((const uint2*)(qin + (size_t)id[k] * DIM))[lx];
            const bool more = (r + 1 < rounds);
            if (more) LIDS(idn, (r + 1) * 8);
            #pragma unroll
            for (int k = 0; k < 8; ++k) {
                const float2 mv = metal[id[k] >> 5];   // LDS broadcast (uniform per stream)
                const float s = mv.x;
                const uint x0 = qv[k].x, x1 = qv[k].y;
                a[0] = fmaf((float)(x0 & 0xffu),         s, a[0]);
                a[1] = fmaf((float)((x0 >> 8) & 0xffu),  s, a[1]);
                a[2] = fmaf((float)((x0 >> 16) & 0xffu), s, a[2]);
                a[3] = fmaf((float)(x0 >> 24),           s, a[3]);
                a[4] = fmaf((float)(x1 & 0xffu),         s, a[4]);
                a[5] = fmaf((float)((x1 >> 8) & 0xffu),  s, a[5]);
                a[6] = fmaf((float)((x1 >> 16) & 0xffu), s, a[6]);
                a[7] = fmaf((float)(x1 >> 24),           s, a[7]);
                O += mv.y;
            }
            if (more) {
                #pragma unroll
                for (int k = 0; k < 8; ++k) id[k] = idn[k];
            }
        }
#undef LIDS

        const float iv = 1.0f / (float)total;
        uint4 p;
        p.x = pack_bf16((a[0] + O) * iv, (a[1] + O) * iv);
        p.y = pack_bf16((a[2] + O) * iv, (a[3] + O) * iv);
        p.z = pack_bf16((a[4] + O) * iv, (a[5] + O) * iv);
        p.w = pack_bf16((a[6] + O) * iv, (a[7] + O) * iv);
        *((uint4*)(xs + st * XST + lx * 8)) = p;
    }
    __syncthreads();

    // ---- phase 2: MFMA y = x @ W^T; 8 waves, rows 2x16, cols 4x32 ----
    {
        const int wave = t >> 6, lane = t & 63;
        const int row_off = (wave >> 2) * 16;
        const int col_off = (wave & 3) * 32;
        const int lm   = lane & 15;
        const int quad = lane >> 4;
        f32x4 acc[2] = {f32x4{0,0,0,0}, f32x4{0,0,0,0}};
        const ushort* xrow = xs + (row_off + lm) * XST + quad * 8;   // LDS
        const ushort* __restrict__ wrow = wb + (size_t)(col_off + lm) * DIM + quad * 8;
        #pragma unroll
        for (int kk = 0; kk < 4; ++kk) {
            const bf16x8 af = __builtin_bit_cast(bf16x8, *(const u32x4*)(xrow + kk * 32));
            #pragma unroll
            for (int c = 0; c < 2; ++c) {
                const bf16x8 bfr = __builtin_bit_cast(bf16x8,
                    *(const u32x4*)(wrow + (size_t)c * 16 * DIM + kk * 32));
                acc[c] = __builtin_amdgcn_mfma_f32_16x16x32_bf16(af, bfr, acc[c], 0, 0, 0);
            }
        }
        #pragma unroll
        for (int c = 0; c < 2; ++c) {
            #pragma unroll
            for (int r = 0; r < 4; ++r)
                ys[(row_off + quad * 4 + r) * RST + col_off + c * 16 + lm] = acc[c][r];
        }
    }
    __syncthreads();

    // ---- phase 3: LN + ELU; group (32-row) requant or fp32 out ----
    {
        const int r   = t >> 4;              // row 0..31
        const int seg = t & 15;              // 0..15
        const int db  = seg * 8;
        const float* yr = ys + r * RST + db;
        float vs[8];
        {
            const float4 y0 = ((const float4*)yr)[0];
            const float4 y1 = ((const float4*)yr)[1];
            const float4 b0 = ((const float4*)(bias + db))[0];
            const float4 b1 = ((const float4*)(bias + db))[1];
            vs[0] = y0.x + b0.x; vs[1] = y0.y + b0.y; vs[2] = y0.z + b0.z; vs[3] = y0.w + b0.w;
            vs[4] = y1.x + b1.x; vs[5] = y1.y + b1.y; vs[6] = y1.z + b1.z; vs[7] = y1.w + b1.w;
        }
        float s1 = 0.0f, s2 = 0.0f;
        #pragma unroll
        for (int i = 0; i < 8; ++i) { s1 += vs[i]; s2 += vs[i] * vs[i]; }
        #pragma unroll
        for (int m = 1; m < 16; m <<= 1) {
            s1 += __shfl_xor(s1, m);
            s2 += __shfl_xor(s2, m);
        }
        const float mu  = s1 * (1.0f / 128.0f);
        const float var = s2 * (1.0f / 128.0f) - mu * mu;
        const float rs  = rsqrtf(var + LN_EPS);
        float ov[8];
        {
            const float4 g0 = ((const float4*)(gamma + db))[0];
            const float4 g1 = ((const float4*)(gamma + db))[1];
            const float4 t0 = ((const float4*)(beta + db))[0];
            const float4 t1 = ((const float4*)(beta + db))[1];
            float z;
            z = (vs[0] - mu) * rs * g0.x + t0.x; ov[0] = (z > 0.0f) ? z : __expf(z) - 1.0f;
            z = (vs[1] - mu) * rs * g0.y + t0.y; ov[1] = (z > 0.0f) ? z : __expf(z) - 1.0f;
            z = (vs[2] - mu) * rs * g0.z + t0.z; ov[2] = (z > 0.0f) ? z : __expf(z) - 1.0f;
            z = (vs[3] - mu) * rs * g0.w + t0.w; ov[3] = (z > 0.0f) ? z : __expf(z) - 1.0f;
            z = (vs[4] - mu) * rs * g1.x + t1.x; ov[4] = (z > 0.0f) ? z : __expf(z) - 1.0f;
            z = (vs[5] - mu) * rs * g1.y + t1.y; ov[5] = (z > 0.0f) ? z : __expf(z) - 1.0f;
            z = (vs[6] - mu) * rs * g1.z + t1.z; ov[6] = (z > 0.0f) ? z : __expf(z) - 1.0f;
            z = (vs[7] - mu) * rs * g1.w + t1.w; ov[7] = (z > 0.0f) ? z : __expf(z) - 1.0f;
        }
        const int slot = rows + r;
        if (OUT_FP32) {
            if (slot < nrows) {
                float* op = fpout + (size_t)slot * DIM + db;
                ((float4*)op)[0] = make_float4(ov[0], ov[1], ov[2], ov[3]);
                ((float4*)op)[1] = make_float4(ov[4], ov[5], ov[6], ov[7]);
            }
        } else {
            const bool valid = slot < nrows;
            float mn = valid ? ov[0] : 3.4e38f;
            float mx = valid ? ov[0] : -3.4e38f;
            if (valid) {
                #pragma unroll
                for (int j = 1; j < 8; ++j) { mn = fminf(mn, ov[j]); mx = fmaxf(mx, ov[j]); }
            }
            #pragma unroll
            for (int m = 1; m < 16; m <<= 1) {
                mn = fminf(mn, __shfl_xor(mn, m));
                mx = fmaxf(mx, __shfl_xor(mx, m));
            }
            if (seg == 0) { rmn[r] = mn; rmx[r] = mx; }
            __syncthreads();
            float gmn = rmn[0], gmx = rmx[0];
            #pragma unroll
            for (int i = 1; i < 32; ++i) { gmn = fminf(gmn, rmn[i]); gmx = fmaxf(gmx, rmx[i]); }
            const float rng = gmx - gmn;
            const float rcp = (rng > 0.0f) ? 255.0f / rng : 0.0f;
            if (valid) {
                uint bq[8];
                #pragma unroll
                for (int j = 0; j < 8; ++j)
                    bq[j] = (uint)fminf(255.0f, fmaf(ov[j] - gmn, rcp, 0.5f));
                uint2 q;
                q.x = bq[0] | (bq[1] << 8) | (bq[2] << 16) | (bq[3] << 24);
                q.y = bq[4] | (bq[5] << 8) | (bq[6] << 16) | (bq[7] << 24);
                ((uint2*)(qout + (size_t)slot * DIM))[seg] = q;
            }
            if (t == 0) mgout[blockIdx.x] = make_float2(rng * (1.0f / 255.0f), gmn);
        }
    }
}

extern "C" void kernel_launch(void* const* d_in, const int* in_sizes, int n_in,
                              void* d_out, int out_size, void* d_ws, size_t ws_size,
                              hipStream_t stream) {
    const float* emb   = (const float*)d_in[0];
    const float* W     = (const float*)d_in[1];
    const float* bias  = (const float*)d_in[2];
    const float* gamma = (const float*)d_in[3];
    const float* beta  = (const float*)d_in[4];
    const int*   src   = (const int*)d_in[5];
    const int*   dst   = (const int*)d_in[6];
    const int*   uid   = (const int*)d_in[7];

    // workspace (~28 MB); Q buffers sized QROWS rows (pad rows readable; pad GROUP
    // meta = (0,0) so pad contributions are exactly zero regardless of pad bytes)
    const size_t QSZ = (size_t)QROWS * DIM;           // bytes per int8 feature buffer
    uchar*  Q0  = (uchar*)d_ws;
    uchar*  Q1  = Q0 + QSZ;
    uchar*  Q2  = Q1 + QSZ;
    ushort* WB  = (ushort*)(Q2 + QSZ);                // 3*128*128 bf16
    float2* MG0 = (float2*)(WB + 3 * DIM * DIM);      // PGRP+1 group metas (+pad to 1568)
    float2* MG1 = MG0 + 1568;
    float2* MG2 = MG1 + 1568;
    int*    off  = (int*)(MG2 + 1568);                // 50000 (+pad)
    int*    degv = off + (N_NODES + 4);               // 50000 (+pad)
    int*    bcur = degv + (N_NODES + 4);              // NBUCK (+pad)
    int*    pak  = bcur + (NBUCK + 2);                // NBUCK*BCAP packed (src<<6)|(dst&63)
    int*    csr  = pak + NBUCK * BCAP;                // NBUCK*BCAP + overread slack

    prep_kernel<<<PGRP + 24 + 1, 512, 0, stream>>>(emb, Q0, MG0, W, WB, bcur, MG1, MG2);
    part_kernel<<<NCHUNK, 256, 0, stream>>>(src, dst, bcur, pak);
    bucket_kernel<<<NBUCK, 256, 0, stream>>>(pak, bcur, off, degv, csr);

    const int lblk = (N_NODES + 31) / 32;             // 1563

    // layer 1: Q0 -> Q1
    layer_kernel<false><<<lblk, 512, 0, stream>>>(Q0, MG0, Q1, MG1, nullptr,
                                                  off, degv, csr, nullptr, WB,
                                                  bias, gamma, beta, N_NODES);
    // layer 2: Q1 -> Q2
    layer_kernel<false><<<lblk, 512, 0, stream>>>(Q1, MG1, Q2, MG2, nullptr,
                                                  off, degv, csr, nullptr, WB + DIM * DIM,
                                                  bias + DIM, gamma + DIM, beta + DIM, N_NODES);
    // layer 3: uid nodes only, Q2 -> d_out (fp32, no requant)
    layer_kernel<true><<<N_UID / 32, 512, 0, stream>>>(Q2, MG2, nullptr, nullptr, (float*)d_out,
                                                       off, degv, csr, uid, WB + 2 * DIM * DIM,
                                                       bias + 2 * DIM, gamma + 2 * DIM,
                                                       beta + 2 * DIM, N_UID);
}